// Round 23
// baseline (68.634 us; speedup 1.0000x reference)
//
#include <hip/hip_runtime.h>

#define BS 4096
#define LL 512
#define NB 8                  // batches per block (MFMA cols 8..15 duplicate 0..7)
#define NCH 32                // chunks of 16 steps
#define HT 256                // timesteps staged per half
#define RSD 33                // dwords per staged t-row (32 data + 1 pad)
#define START_TAG 1
#define END_TAG 2
#define BIASF 4.5f            // per-applied-step 2^-BIASF (restored exactly in log2)
#define L2E 1.44269504f
#define LN2 0.69314718055994531f

typedef float f32x4 __attribute__((ext_vector_type(4)));
typedef short s16x4 __attribute__((ext_vector_type(4)));
union BF4 { unsigned u[2]; s16x4 s; };

__device__ __forceinline__ unsigned cvt_pk_bf16(float lo, float hi) {
    unsigned r;
    asm("v_cvt_pk_bf16_f32 %0, %1, %2" : "=v"(r) : "v"(lo), "v"(hi));
    return r;
}
__device__ __forceinline__ unsigned pkrtz(float lo, float hi) {
    unsigned r;
    asm("v_cvt_pkrtz_f16_f32 %0, %1, %2" : "=v"(r) : "v"(lo), "v"(hi));
    return r;
}
__device__ __forceinline__ float cf16(unsigned bits) {
    float f;
    asm("v_cvt_f32_f16 %0, %1" : "=v"(f) : "v"(bits));
    return f;
}
__device__ __forceinline__ float blo(unsigned u) { return __uint_as_float(u << 16); }
__device__ __forceinline__ float bhi(unsigned u) { return __uint_as_float(u & 0xFFFF0000u); }

// fp8(e5m2)-scale chain step (r22-validated): decode 4 scales, MFMA, repack
#define CSTEP8(S8, P01, P23) { \
        const float f0 = cf16(((S8) & 0xFFu) << 8); \
        const float f1 = cf16((S8) & 0xFF00u); \
        const float f2 = cf16(((S8) >> 8) & 0xFF00u); \
        const float f3 = cf16(((S8) >> 16) & 0xFF00u); \
        BF4 Bf; Bf.u[0] = P01; Bf.u[1] = P23; \
        f32x4 z = {0.f, 0.f, 0.f, 0.f}; \
        f32x4 d = __builtin_amdgcn_mfma_f32_16x16x16bf16_1k(Af.s, Bf.s, z, 0, 0, 0); \
        P01 = cvt_pk_bf16(d[0] * f0, d[1] * f1); \
        P23 = cvt_pk_bf16(d[2] * f2, d[3] * f3); }

#define CSTEP8M(S8, MB, S, P01, P23) { \
        const float f0 = cf16(((S8) & 0xFFu) << 8); \
        const float f1 = cf16((S8) & 0xFF00u); \
        const float f2 = cf16(((S8) >> 8) & 0xFF00u); \
        const float f3 = cf16(((S8) >> 16) & 0xFF00u); \
        BF4 Bf; Bf.u[0] = P01; Bf.u[1] = P23; \
        f32x4 z = {0.f, 0.f, 0.f, 0.f}; \
        f32x4 d = __builtin_amdgcn_mfma_f32_16x16x16bf16_1k(Af.s, Bf.s, z, 0, 0, 0); \
        const unsigned n01 = cvt_pk_bf16(d[0] * f0, d[1] * f1); \
        const unsigned n23 = cvt_pk_bf16(d[2] * f2, d[3] * f3); \
        const bool up = (((MB) >> (S)) & 1u) != 0u; \
        P01 = up ? n01 : P01; \
        P23 = up ? n23 : P23; }

#define RENORM(P01, P23, E2F) { \
        const float v0 = blo(P01), v1 = bhi(P01), v2 = blo(P23), v3 = bhi(P23); \
        float mm = fmaxf(fmaxf(v0, v1), fmaxf(v2, v3)); \
        mm = fmaxf(mm, __shfl_xor(mm, 16)); \
        mm = fmaxf(mm, __shfl_xor(mm, 32)); \
        if (mm > 0.f) { \
            const int ex = (int)((__float_as_uint(mm) >> 23) & 0xFFu) - 127; \
            const float sre = __uint_as_float((unsigned)(127 - ex) << 23); \
            E2F += (float)ex; \
            P01 = cvt_pk_bf16(v0 * sre, v1 * sre); \
            P23 = cvt_pk_bf16(v2 * sre, v3 * sre); } }

// Two independent 16-step chunks advanced alternately (r18-validated ILP-2),
// scales from fp8 LDS, 1-step-ahead rolling prefetch.
__device__ __forceinline__ void chain16_dual8(
    const unsigned* __restrict__ sSCu, int ta, int tb, int jqo, const BF4& Af,
    unsigned mba, unsigned mbb,
    unsigned& a01, unsigned& a23, unsigned& b01, unsigned& b23,
    float& ea, float& eb)
{
    const int basea = ta * RSD + jqo;
    const int baseb = tb * RSD + jqo;
    unsigned svA = sSCu[basea];
    unsigned svB = sSCu[baseb];
    if (__all((mba == 0xFFFFu) & (mbb == 0xFFFFu))) {
#pragma unroll
        for (int s = 0; s < 16; ++s) {
            const unsigned nA = (s < 15) ? sSCu[basea + (s + 1) * RSD] : svA;
            const unsigned nB = (s < 15) ? sSCu[baseb + (s + 1) * RSD] : svB;
            CSTEP8(svA, a01, a23)
            CSTEP8(svB, b01, b23)
            svA = nA; svB = nB;
        }
    } else {
#pragma unroll
        for (int s = 0; s < 16; ++s) {
            const unsigned nA = (s < 15) ? sSCu[basea + (s + 1) * RSD] : svA;
            const unsigned nB = (s < 15) ? sSCu[baseb + (s + 1) * RSD] : svB;
            CSTEP8M(svA, mba, s, a01, a23)
            CSTEP8M(svB, mbb, s, b01, b23)
            svA = nA; svB = nB;
        }
    }
    RENORM(a01, a23, ea)
    RENORM(b01, b23, eb)
}

// Small-block CRF for multi-block/CU residency: block = 8 batches, 8 waves,
// ~47.7 KB LDS -> 3 blocks/CU. Two staged halves (fp8 e5m2 scales); per half:
// stage -> score -> pass1 (chunks {wv, wv+8} dual) -> pass2 (from y_{c-1}).
// r17/r22-validated math throughout; telescoped rank-1 combine.
__global__ __launch_bounds__(512, 6) void crf_mb(
    const float* __restrict__ em, const int* __restrict__ tg,
    const float* __restrict__ mk, const float* __restrict__ tr,
    float* __restrict__ out)
{
    __shared__ unsigned sSCu[HT * RSD];            // 33792 B fp8 scales
    __shared__ unsigned sYp[NCH * NB * 8];         // 8 KB packed bf16 y-vectors
    __shared__ float sYs[NCH][NB], sRs[NCH][NB], sF[NCH][NB], sG[NCH][NB];
    __shared__ unsigned short sMB[NCH][NB];        // per-(chunk,batch) mask bits
    __shared__ float sTR[256];
    __shared__ float sSc[NB], sRes[NB];

    const int tid = threadIdx.x;
    const int wv = tid >> 6, lane = tid & 63;
    const int j = lane & 15, q = lane >> 4;
    const int jj = j & 7;                          // batch (cols 8..15 duplicate)
    const long gb0 = (long)blockIdx.x * NB;

    if (tid < 64) *(f32x4*)(sTR + tid * 4) = *(const f32x4*)(tr + tid * 4);

    int is64 = 1;
    {
        const unsigned long long* t64 = (const unsigned long long*)tg;
#pragma unroll
        for (int i = 0; i < 16; ++i) is64 &= (t64[i] < 16ull) ? 1 : 0;
    }
    const int esz = is64 ? 2 : 1;

    // mask bitmask: wave wv = batch wv (validated)
    {
        const float* mp = mk + (gb0 + wv) * (long)LL;
#pragma unroll
        for (int k = 0; k < 8; ++k) {
            const unsigned long long bal = __ballot(mp[k * 64 + lane] > 0.f);
            if (lane == 0) {
                sMB[4 * k + 0][wv] = (unsigned short)(bal);
                sMB[4 * k + 1][wv] = (unsigned short)(bal >> 16);
                sMB[4 * k + 2][wv] = (unsigned short)(bal >> 32);
                sMB[4 * k + 3][wv] = (unsigned short)(bal >> 48);
            }
        }
    }
    __syncthreads();

    // static A = E^T (validated): lane (j,q) holds A[j][4q+i] = exp(tr[4q+i][j])
    BF4 Af;
    {
        float Ef[4];
#pragma unroll
        for (int i = 0; i < 4; ++i)
            Ef[i] = exp2f(sTR[(q * 4 + i) * 16 + j] * L2E);   // exp(-1000) -> 0
        Af.u[0] = cvt_pk_bf16(Ef[0], Ef[1]);
        Af.u[1] = cvt_pk_bf16(Ef[2], Ef[3]);
    }
    const int jqo = jj * 4 + q;                    // dword index in staged row

    float scoreAcc = 0.f;

    for (int h = 0; h < 2; ++h) {
        // ---- stage half h: coalesced em -> exp2 -> fp8 e5m2 -> LDS ----
#pragma unroll 4
        for (int it = 0; it < 16; ++it) {
            const int qid = tid + it * 512;        // [b:3][t:8][q:2] = 8192
            const int bl = qid >> 10, trow = (qid >> 2) & 255, c4 = qid & 3;
            const f32x4 v = *(const f32x4*)(em + ((gb0 + bl) * (long)LL + h * HT + trow) * 16 + 4 * c4);
            const float e0 = exp2f(fmaf(v.x, L2E, -BIASF));
            const float e1 = exp2f(fmaf(v.y, L2E, -BIASF));
            const float e2 = exp2f(fmaf(v.z, L2E, -BIASF));
            const float e3 = exp2f(fmaf(v.w, L2E, -BIASF));
            const unsigned t0 = pkrtz(e0, e1) + 0x00800080u;   // round bit7 half-up
            const unsigned t1 = pkrtz(e2, e3) + 0x00800080u;
            const unsigned b = ((t0 >> 8) & 0xFFu) | (((t0 >> 24) & 0xFFu) << 8)
                             | (((t1 >> 8) & 0xFFu) << 16) | ((t1 >> 24) << 24);
            sSCu[trow * RSD + bl * 4 + c4] = b;
        }
        __syncthreads();

        // ---- score half h (wave wv = batch wv) from fp8 scales (r22 math) ----
        {
            const long bb = (gb0 + wv) * (long)LL;
            const unsigned char* sc8 = (const unsigned char*)sSCu;
#pragma unroll
            for (int k = 0; k < 4; ++k) {
                const int tl = k * 64 + lane;
                const int t = h * HT + tl;
                const int tcur = tg[(bb + t) * esz];
                const long pidx = (bb + (t == 0 ? 1 : t) - 1) * esz;   // in-bounds
                const int tpv = (t == 0) ? START_TAG : (int)tg[pidx];
                const float mbit = (float)((sMB[t >> 4][wv] >> (t & 15)) & 1);
                const float scm = (t == 0) ? 1.f : mbit;
                const float sc = cf16(((unsigned)sc8[tl * (RSD * 4) + wv * 16 + tcur]) << 8);
                const float emr = (log2f(fmaxf(sc, 1e-30f)) + BIASF) * LN2;
                scoreAcc = fmaf(emr + sTR[tpv * 16 + tcur], scm, scoreAcc);
            }
        }

        // ---- pass1: chunks c1 = h*16+wv, c2 = c1+8, from ones (dual, r18) ----
        const int c1 = h * 16 + wv, c2 = c1 + 8;
        const unsigned mb1 = (unsigned)sMB[c1][jj];
        const unsigned mb2 = (unsigned)sMB[c2][jj];
        {
            unsigned a01 = 0x3F803F80u, a23 = 0x3F803F80u;
            unsigned b01 = 0x3F803F80u, b23 = 0x3F803F80u;
            float ea = 0.f, eb = 0.f;
            chain16_dual8(sSCu, wv * 16, (wv + 8) * 16, jqo, Af,
                          mb1, mb2, a01, a23, b01, b23, ea, eb);
            uint2 ya; ya.x = a01; ya.y = a23;
            uint2 yb; yb.x = b01; yb.y = b23;
            *(uint2*)(sYp + (c1 * NB + jj) * 8 + 2 * q) = ya;
            *(uint2*)(sYp + (c2 * NB + jj) * 8 + 2 * q) = yb;
            float sa = blo(a01) + bhi(a01) + blo(a23) + bhi(a23);
            float sb = blo(b01) + bhi(b01) + blo(b23) + bhi(b23);
            sa += __shfl_xor(sa, 16); sa += __shfl_xor(sa, 32);
            sb += __shfl_xor(sb, 16); sb += __shfl_xor(sb, 32);
            if (lane < 8) {
                sYs[c1][jj] = sa; sF[c1][jj] = ea + BIASF * (float)__popc(mb1);
                sYs[c2][jj] = sb; sF[c2][jj] = eb + BIASF * (float)__popc(mb2);
            }
        }
        __syncthreads();

        // ---- pass2: same chunks from y_{c-1} (c1==0 computed, discarded) ----
        {
            const int p1 = (c1 > 0) ? (c1 - 1) : 0;
            const uint2 y1 = *(const uint2*)(sYp + (p1 * NB + jj) * 8 + 2 * q);
            const uint2 y2 = *(const uint2*)(sYp + ((c2 - 1) * NB + jj) * 8 + 2 * q);
            unsigned a01 = y1.x, a23 = y1.y, b01 = y2.x, b23 = y2.y;
            float ea = 0.f, eb = 0.f;
            chain16_dual8(sSCu, wv * 16, (wv + 8) * 16, jqo, Af,
                          mb1, mb2, a01, a23, b01, b23, ea, eb);
            float sa = blo(a01) + bhi(a01) + blo(a23) + bhi(a23);
            float sb = blo(b01) + bhi(b01) + blo(b23) + bhi(b23);
            sa += __shfl_xor(sa, 16); sa += __shfl_xor(sa, 32);
            sb += __shfl_xor(sb, 16); sb += __shfl_xor(sb, 32);
            if (lane < 8) {
                sRs[c1][jj] = sa; sG[c1][jj] = ea + BIASF * (float)__popc(mb1);
                sRs[c2][jj] = sb; sG[c2][jj] = eb + BIASF * (float)__popc(mb2);
            }
        }
        __syncthreads();
    }

    // ---- score reduce ----
#pragma unroll
    for (int o = 1; o <= 32; o <<= 1) scoreAcc += __shfl_xor(scoreAcc, o);
    if (lane == 0) sSc[wv] = scoreAcc;
    __syncthreads();

    // ---- combine (validated telescope): 128 threads = 8 batches x 16 rows ----
    if (tid < 128) {
        const int b = tid >> 4, row = tid & 15;
        const unsigned short* yp16 = (const unsigned short*)sYp;
        float x = __uint_as_float(((unsigned)yp16[((NCH - 1) * NB + b) * 16 + row]) << 16)
                * exp2f(sTR[row * 16 + END_TAG] * L2E);
#pragma unroll
        for (int o = 1; o <= 8; o <<= 1) x += __shfl_xor(x, o, 16);
        if (row == 0) {
            float l2 = log2f(fmaxf(x, 1e-37f)) + sF[NCH - 1][b];
#pragma unroll
            for (int c = 1; c < NCH; ++c)
                l2 += log2f(fmaxf(sRs[c][b], 1e-37f))
                    - log2f(fmaxf(sYs[c][b], 1e-37f))
                    + sG[c][b] + sF[c - 1][b] - sF[c][b];
            int cnt = 0;
#pragma unroll
            for (int c = 0; c < NCH; ++c) cnt += __popc((unsigned)sMB[c][b]);
            const int li = (cnt > 0) ? (cnt - 1) : 0;
            const int lt = tg[((gb0 + b) * (long)LL + li) * esz];
            sRes[b] = LN2 * l2 - (sSc[b] + sTR[lt * 16 + END_TAG]);
        }
    }
    __syncthreads();
    if (tid == 0) {
        float s = 0.f;
#pragma unroll
        for (int i = 0; i < NB; ++i) s += sRes[i];
        atomicAdd(out, s);
    }
}

extern "C" void kernel_launch(void* const* d_in, const int* in_sizes, int n_in,
                              void* d_out, int out_size, void* d_ws, size_t ws_size,
                              hipStream_t stream) {
    const float* em = (const float*)d_in[0];
    const int*   tg = (const int*)d_in[1];
    const float* mk = (const float*)d_in[2];
    const float* tr = (const float*)d_in[3];
    float* out = (float*)d_out;

    hipMemsetAsync(out, 0, sizeof(float), stream);
    crf_mb<<<BS / NB, 512, 0, stream>>>(em, tg, mk, tr, out);
}

// Round 24
// 60.014 us; speedup vs baseline: 1.1436x; 1.1436x over previous
//
#include <hip/hip_runtime.h>

#define BS 4096
#define LL 512
#define NB 16                 // batches per block = MFMA columns
#define NCH 32                // chunks of 16 steps
#define RSD 66                // dwords per staged t-row (64 data + 2 pad; 2-way banks)
#define START_TAG 1
#define END_TAG 2
#define BIASF 4.5f            // per-applied-step 2^-BIASF (restored exactly in log2)
#define L2E 1.44269504f
#define LN2 0.69314718055994531f

typedef float f32x4 __attribute__((ext_vector_type(4)));
typedef short s16x4 __attribute__((ext_vector_type(4)));
union BF4 { unsigned u[2]; s16x4 s; };

__device__ __forceinline__ unsigned cvt_pk_bf16(float lo, float hi) {
    unsigned r;
    asm("v_cvt_pk_bf16_f32 %0, %1, %2" : "=v"(r) : "v"(lo), "v"(hi));
    return r;
}
__device__ __forceinline__ unsigned pkrtz(float lo, float hi) {
    unsigned r;
    asm("v_cvt_pkrtz_f16_f32 %0, %1, %2" : "=v"(r) : "v"(lo), "v"(hi));
    return r;
}
__device__ __forceinline__ float cf16(unsigned bits) {
    float f;
    asm("v_cvt_f32_f16 %0, %1" : "=v"(f) : "v"(bits));
    return f;
}
__device__ __forceinline__ float blo(unsigned u) { return __uint_as_float(u << 16); }
__device__ __forceinline__ float bhi(unsigned u) { return __uint_as_float(u & 0xFFFF0000u); }
__device__ __forceinline__ float fexp2(float x) { return __builtin_amdgcn_exp2f(x); }

// fp8(e5m2)-scale chain step (r22-validated): decode 4 scales, MFMA, repack
#define CSTEP8(S8, P01, P23) { \
        const float f0 = cf16(((S8) & 0xFFu) << 8); \
        const float f1 = cf16((S8) & 0xFF00u); \
        const float f2 = cf16(((S8) >> 8) & 0xFF00u); \
        const float f3 = cf16(((S8) >> 16) & 0xFF00u); \
        BF4 Bf; Bf.u[0] = P01; Bf.u[1] = P23; \
        f32x4 z = {0.f, 0.f, 0.f, 0.f}; \
        f32x4 d = __builtin_amdgcn_mfma_f32_16x16x16bf16_1k(Af.s, Bf.s, z, 0, 0, 0); \
        P01 = cvt_pk_bf16(d[0] * f0, d[1] * f1); \
        P23 = cvt_pk_bf16(d[2] * f2, d[3] * f3); }

#define CSTEP8M(S8, MB, S, P01, P23) { \
        const float f0 = cf16(((S8) & 0xFFu) << 8); \
        const float f1 = cf16((S8) & 0xFF00u); \
        const float f2 = cf16(((S8) >> 8) & 0xFF00u); \
        const float f3 = cf16(((S8) >> 16) & 0xFF00u); \
        BF4 Bf; Bf.u[0] = P01; Bf.u[1] = P23; \
        f32x4 z = {0.f, 0.f, 0.f, 0.f}; \
        f32x4 d = __builtin_amdgcn_mfma_f32_16x16x16bf16_1k(Af.s, Bf.s, z, 0, 0, 0); \
        const unsigned n01 = cvt_pk_bf16(d[0] * f0, d[1] * f1); \
        const unsigned n23 = cvt_pk_bf16(d[2] * f2, d[3] * f3); \
        const bool up = (((MB) >> (S)) & 1u) != 0u; \
        P01 = up ? n01 : P01; \
        P23 = up ? n23 : P23; }

#define RENORM(P01, P23, E2F) { \
        const float v0 = blo(P01), v1 = bhi(P01), v2 = blo(P23), v3 = bhi(P23); \
        float mm = fmaxf(fmaxf(v0, v1), fmaxf(v2, v3)); \
        mm = fmaxf(mm, __shfl_xor(mm, 16)); \
        mm = fmaxf(mm, __shfl_xor(mm, 32)); \
        if (mm > 0.f) { \
            const int ex = (int)((__float_as_uint(mm) >> 23) & 0xFFu) - 127; \
            const float sre = __uint_as_float((unsigned)(127 - ex) << 23); \
            E2F += (float)ex; \
            P01 = cvt_pk_bf16(v0 * sre, v1 * sre); \
            P23 = cvt_pk_bf16(v2 * sre, v3 * sre); } }

// one 16-step chunk chain from fp8 LDS scales — ROLLED (code-size experiment)
__device__ __noinline__ void chain16_rolled(
    const unsigned* __restrict__ sSCu, int base, const BF4& Af, unsigned mbc,
    unsigned& P01, unsigned& P23, float& E2F)
{
    unsigned p01 = P01, p23 = P23;
    float e2f = E2F;
    unsigned sv = sSCu[base];
    if (__all(mbc == 0xFFFFu)) {
#pragma unroll 1
        for (int s = 0; s < 15; ++s) {
            const unsigned nx = sSCu[base + (s + 1) * RSD];
            CSTEP8(sv, p01, p23)
            sv = nx;
        }
        CSTEP8(sv, p01, p23)
    } else {
#pragma unroll 1
        for (int s = 0; s < 15; ++s) {
            const unsigned nx = sSCu[base + (s + 1) * RSD];
            CSTEP8M(sv, mbc, s, p01, p23)
            sv = nx;
        }
        CSTEP8M(sv, mbc, 15, p01, p23)
    }
    RENORM(p01, p23, e2f)
    P01 = p01; P23 = p23; E2F = e2f;
}

// Single-stage CRF (r22 structure verbatim, rolled loops + builtin exp2):
// stage ALL 512 steps as fp8 e5m2 scales -> LDS; pass1 chunks {wv, wv+16} from
// ones; pass2 from y_{c-1}; score from staged scales; telescoped combine.
__global__ __launch_bounds__(1024) void crf_f8r(
    const float* __restrict__ em, const int* __restrict__ tg,
    const float* __restrict__ mk, const float* __restrict__ tr,
    float* __restrict__ out)
{
    __shared__ unsigned sSCu[LL * RSD];            // 135168 B fp8 scales
    __shared__ unsigned sYp[NCH * NB * 8];         // 16 KB packed bf16 y-vectors
    __shared__ float sYs[NCH][NB], sRs[NCH][NB], sF[NCH][NB], sG[NCH][NB];
    __shared__ unsigned short sMB[NCH][NB];        // per-(chunk,batch) mask bits
    __shared__ float sTR[256];
    __shared__ float sSc[NB], sRes[NB];

    const int tid = threadIdx.x;
    const int wv = tid >> 6, lane = tid & 63;
    const int j = lane & 15, q = lane >> 4;
    const long gb0 = (long)blockIdx.x * NB;

    if (tid < 64) *(f32x4*)(sTR + tid * 4) = *(const f32x4*)(tr + tid * 4);

    int is64 = 1;
    {
        const unsigned long long* t64 = (const unsigned long long*)tg;
#pragma unroll
        for (int i = 0; i < 16; ++i) is64 &= (t64[i] < 16ull) ? 1 : 0;
    }
    const int esz = is64 ? 2 : 1;

    // mask bitmask: wave wv = batch wv (r17 verbatim)
    {
        const float* mp = mk + (gb0 + wv) * (long)LL;
#pragma unroll
        for (int k = 0; k < 8; ++k) {
            const unsigned long long bal = __ballot(mp[k * 64 + lane] > 0.f);
            if (lane == 0) {
                sMB[4 * k + 0][wv] = (unsigned short)(bal);
                sMB[4 * k + 1][wv] = (unsigned short)(bal >> 16);
                sMB[4 * k + 2][wv] = (unsigned short)(bal >> 32);
                sMB[4 * k + 3][wv] = (unsigned short)(bal >> 48);
            }
        }
    }
    __syncthreads();

    // static A = E^T (validated): lane (j,q) holds A[j][4q+i] = exp(tr[4q+i][j])
    BF4 Af;
    {
        float Ef[4];
#pragma unroll
        for (int i = 0; i < 4; ++i)
            Ef[i] = fexp2(sTR[(q * 4 + i) * 16 + j] * L2E);   // exp(-1000) -> 0
        Af.u[0] = cvt_pk_bf16(Ef[0], Ef[1]);
        Af.u[1] = cvt_pk_bf16(Ef[2], Ef[3]);
    }

    // ---- stage ALL 512 steps: coalesced em -> exp2 -> fp8 e5m2 -> LDS ----
#pragma unroll 2
    for (int it = 0; it < 32; ++it) {
        const int qid = tid + it * 1024;           // [b:4][t:9][q:2]
        const int bl = qid >> 11, trow = (qid >> 2) & 511, c4 = qid & 3;
        const f32x4 v = *(const f32x4*)(em + ((gb0 + bl) * (long)LL + trow) * 16 + 4 * c4);
        const float e0 = fexp2(fmaf(v.x, L2E, -BIASF));
        const float e1 = fexp2(fmaf(v.y, L2E, -BIASF));
        const float e2 = fexp2(fmaf(v.z, L2E, -BIASF));
        const float e3 = fexp2(fmaf(v.w, L2E, -BIASF));
        const unsigned t0 = pkrtz(e0, e1) + 0x00800080u;   // round bit7 half-up
        const unsigned t1 = pkrtz(e2, e3) + 0x00800080u;
        const unsigned b = ((t0 >> 8) & 0xFFu) | (((t0 >> 24) & 0xFFu) << 8)
                         | (((t1 >> 8) & 0xFFu) << 16) | ((t1 >> 24) << 24);
        sSCu[trow * RSD + bl * 4 + c4] = b;
    }
    __syncthreads();

    // ---- pass1: wave wv chains chunks {wv, wv+16} from ones ----
#pragma unroll 1
    for (int half = 0; half < 2; ++half) {
        const int c = wv + half * 16;
        const unsigned mbc = (unsigned)sMB[c][j];
        const int base = (c * 16) * RSD + j * 4 + q;
        unsigned p01 = 0x3F803F80u, p23 = 0x3F803F80u;
        float e2f = 0.f;
        chain16_rolled(sSCu, base, Af, mbc, p01, p23, e2f);
        uint2 y; y.x = p01; y.y = p23;
        *(uint2*)(sYp + (c * 16 + j) * 8 + 2 * q) = y;
        float sa = blo(p01) + bhi(p01) + blo(p23) + bhi(p23);
        sa += __shfl_xor(sa, 16);
        sa += __shfl_xor(sa, 32);
        if (lane < 16) {
            sYs[c][j] = sa;
            sF[c][j] = e2f + BIASF * (float)__popc(mbc);
        }
    }
    __syncthreads();

    // ---- pass2: same chunks from y_{c-1}; score fused into this phase ----
#pragma unroll 1
    for (int half = 0; half < 2; ++half) {
        const int c = wv + half * 16;
        if (c > 0) {                               // wave-uniform
            const unsigned mbc = (unsigned)sMB[c][j];
            const int base = (c * 16) * RSD + j * 4 + q;
            const uint2 y = *(const uint2*)(sYp + ((c - 1) * 16 + j) * 8 + 2 * q);
            unsigned r01 = y.x, r23 = y.y;
            float g2f = 0.f;
            chain16_rolled(sSCu, base, Af, mbc, r01, r23, g2f);
            float sb = blo(r01) + bhi(r01) + blo(r23) + bhi(r23);
            sb += __shfl_xor(sb, 16);
            sb += __shfl_xor(sb, 32);
            if (lane < 16) {
                sRs[c][j] = sb;
                sG[c][j] = g2f + BIASF * (float)__popc(mbc);
            }
        }
    }
    // score: wave wv = batch wv, em reconstructed from fp8 scales
    float scoreAcc = 0.f;
    {
        const long bb = (gb0 + wv) * (long)LL;
        const unsigned char* sc8 = (const unsigned char*)sSCu;
#pragma unroll 1
        for (int k = 0; k < 8; ++k) {
            const int t = k * 64 + lane;
            const int tcur = tg[(bb + t) * esz];
            const long pidx = (bb + (t == 0 ? 1 : t) - 1) * esz;   // in-bounds
            const int tpv = (t == 0) ? START_TAG : (int)tg[pidx];
            const float mbit = (float)((sMB[t >> 4][wv] >> (t & 15)) & 1);
            const float scm = (t == 0) ? 1.f : mbit;
            const float sc = cf16(((unsigned)sc8[t * (RSD * 4) + wv * 16 + tcur]) << 8);
            const float emr = (log2f(fmaxf(sc, 1e-30f)) + BIASF) * LN2;
            scoreAcc = fmaf(emr + sTR[tpv * 16 + tcur], scm, scoreAcc);
        }
#pragma unroll
        for (int o = 1; o <= 32; o <<= 1) scoreAcc += __shfl_xor(scoreAcc, o);
        if (lane == 0) sSc[wv] = scoreAcc;
    }
    __syncthreads();

    // ---- combine (r17-validated telescope): 256 threads = 16 b x 16 rows ----
    if (tid < 256) {
        const int b = tid >> 4, row = tid & 15;
        const unsigned short* yp16 = (const unsigned short*)sYp;
        float x = __uint_as_float(((unsigned)yp16[((NCH - 1) * 16 + b) * 16 + row]) << 16)
                * fexp2(sTR[row * 16 + END_TAG] * L2E);
#pragma unroll
        for (int o = 1; o <= 8; o <<= 1) x += __shfl_xor(x, o, 16);
        if (row == 0) {
            float l2 = log2f(fmaxf(x, 1e-37f)) + sF[NCH - 1][b];
#pragma unroll 1
            for (int c2 = 1; c2 < NCH; ++c2)
                l2 += log2f(fmaxf(sRs[c2][b], 1e-37f))
                    - log2f(fmaxf(sYs[c2][b], 1e-37f))
                    + sG[c2][b] + sF[c2 - 1][b] - sF[c2][b];
            int cnt = 0;
#pragma unroll 1
            for (int c2 = 0; c2 < NCH; ++c2) cnt += __popc((unsigned)sMB[c2][b]);
            const int li = (cnt > 0) ? (cnt - 1) : 0;
            const int lt = tg[((gb0 + b) * (long)LL + li) * esz];
            sRes[b] = LN2 * l2 - (sSc[b] + sTR[lt * 16 + END_TAG]);
        }
    }
    __syncthreads();
    if (tid == 0) {
        float s = 0.f;
#pragma unroll
        for (int i = 0; i < NB; ++i) s += sRes[i];
        atomicAdd(out, s);
    }
}

extern "C" void kernel_launch(void* const* d_in, const int* in_sizes, int n_in,
                              void* d_out, int out_size, void* d_ws, size_t ws_size,
                              hipStream_t stream) {
    const float* em = (const float*)d_in[0];
    const int*   tg = (const int*)d_in[1];
    const float* mk = (const float*)d_in[2];
    const float* tr = (const float*)d_in[3];
    float* out = (float*)d_out;

    hipMemsetAsync(out, 0, sizeof(float), stream);
    crf_f8r<<<BS / NB, 1024, 0, stream>>>(em, tg, mk, tr, out);
}